// Round 1
// baseline (377.883 us; speedup 1.0000x reference)
//
#include <hip/hip_runtime.h>

typedef unsigned short u16;
typedef __bf16 bf16x8 __attribute__((ext_vector_type(8)));
typedef float  f32x4  __attribute__((ext_vector_type(4)));

#define SEQ 2048

__device__ __forceinline__ float bf2f(u16 u) {
    union { unsigned int i; float f; } c;
    c.i = ((unsigned int)u) << 16;
    return c.f;
}
__device__ __forceinline__ u16 f2bf(float f) {
    union { float f; unsigned int i; } c;
    c.f = f;
    unsigned int u = c.i;
    u += 0x7FFFu + ((u >> 16) & 1u);   // round-to-nearest-even
    return (u16)(u >> 16);
}

// async global->LDS, 16B per lane; lds dest = wave-uniform base + lane*16
__device__ __forceinline__ void gl_lds16(const u16* g, u16* l) {
    __builtin_amdgcn_global_load_lds(
        (const __attribute__((address_space(1))) unsigned int*)(g),
        (__attribute__((address_space(3))) unsigned int*)(l), 16, 0, 0);
}

__device__ __forceinline__ void cvt4(const float* s, u16* d) {
    float4 v = *(const float4*)s;
    ushort4 o;
    o.x = f2bf(v.x); o.y = f2bf(v.y); o.z = f2bf(v.z); o.w = f2bf(v.w);
    *(ushort4*)d = o;
}

// ---------------------------------------------------------------- fused prep
__global__ void prep(const float* __restrict__ x,
                     const float* __restrict__ wq, const float* __restrict__ wk,
                     const float* __restrict__ wv,
                     const float* __restrict__ bq, const float* __restrict__ bk,
                     const float* __restrict__ bv,
                     u16* __restrict__ xb, u16* __restrict__ wqkvb,
                     float* __restrict__ biasb)
{
    const int E0 = 2097152;            // x float4s
    const int E1 = E0 + 1048576;       // wq
    const int E2 = E1 + 262144;        // wk
    const int E3 = E2 + 262144;        // wv
    const int E4 = E3 + 768;           // bias float4s
    int i = blockIdx.x * blockDim.x + threadIdx.x;
    int stride = gridDim.x * blockDim.x;
    for (; i < E4; i += stride) {
        if (i < E0)      cvt4(x  + (size_t)i * 4,        xb    + (size_t)i * 4);
        else if (i < E1) cvt4(wq + (size_t)(i - E0) * 4, wqkvb + (size_t)(i - E0) * 4);
        else if (i < E2) cvt4(wk + (size_t)(i - E1) * 4, wqkvb + 4194304 + (size_t)(i - E1) * 4);
        else if (i < E3) cvt4(wv + (size_t)(i - E2) * 4, wqkvb + 5242880 + (size_t)(i - E2) * 4);
        else {
            int j = i - E3;            // 0..767
            const float* src = (j < 512) ? (bq + j * 4)
                             : (j < 640) ? (bk + (j - 512) * 4)
                                         : (bv + (j - 640) * 4);
            *(float4*)&biasb[j * 4] = *(const float4*)src;
        }
    }
}

__global__ void cvt_f32_bf16(const float* __restrict__ in, u16* __restrict__ out, int n4) {
    int i = blockIdx.x * blockDim.x + threadIdx.x;
    int stride = gridDim.x * blockDim.x;
    for (; i < n4; i += stride) cvt4(in + (size_t)i * 4, out + (size_t)i * 4);
}

// ---------------------------------------------------------------- GEMM C = A*B^T + bias
// global_load_lds staging (m97 pattern), plain layout (chunk swizzle proven no-op on
// SQ_LDS_BANK_CONFLICT in r4 -> reverted).
// MODE 0: C fp32. MODE 1: qkv split q/k natural (B,H,S,128), v transposed (B,4,128,S).
template<int MODE>
__global__ __launch_bounds__(256) void gemm_bt(
    const u16* __restrict__ A, const u16* __restrict__ B,
    const float* __restrict__ bias, float* __restrict__ C,
    u16* __restrict__ qb, u16* __restrict__ kb, u16* __restrict__ vt,
    int M, int N, int K)
{
    __shared__ __align__(16) u16 lA[128 * 32];
    __shared__ __align__(16) u16 lB[128 * 32];
    const int tid   = threadIdx.x;
    const int lane  = tid & 63;
    const int wave  = tid >> 6;
    const int waveM = (wave >> 1) * 64;
    const int waveN = (wave & 1) * 64;
    const int bm = blockIdx.x * 128;
    const int bn = blockIdx.y * 128;
    const int lrow = lane & 15;
    const int koff = (lane >> 4) * 8;

    f32x4 acc[4][4] = {};

    for (int k0 = 0; k0 < K; k0 += 32) {
        __syncthreads();
#pragma unroll
        for (int p = 0; p < 2; ++p) {
            int idx = p * 256 + tid;    // 0..511
            int row = idx >> 2;         // 0..127
            int ch  = idx & 3;          // 16B chunk
            gl_lds16(&A[(size_t)(bm + row) * K + k0 + ch * 8], &lA[(p * 256 + wave * 64) * 8]);
            gl_lds16(&B[(size_t)(bn + row) * K + k0 + ch * 8], &lB[(p * 256 + wave * 64) * 8]);
        }
        __syncthreads();

        bf16x8 af[4], bfr[4];
#pragma unroll
        for (int i = 0; i < 4; ++i)
            af[i] = *(const bf16x8*)&lA[(waveM + i * 16 + lrow) * 32 + koff];
#pragma unroll
        for (int j = 0; j < 4; ++j)
            bfr[j] = *(const bf16x8*)&lB[(waveN + j * 16 + lrow) * 32 + koff];
#pragma unroll
        for (int i = 0; i < 4; ++i)
#pragma unroll
            for (int j = 0; j < 4; ++j)
                acc[i][j] = __builtin_amdgcn_mfma_f32_16x16x32_bf16(
                    af[i], bfr[j], acc[i][j], 0, 0, 0);
    }

    const int r4 = (lane >> 4) * 4;
    const int cn = lane & 15;
#pragma unroll
    for (int i = 0; i < 4; ++i) {
#pragma unroll
        for (int j = 0; j < 4; ++j) {
            int row0 = bm + waveM + i * 16 + r4;
            int col  = bn + waveN + j * 16 + cn;
            float bc = bias[col];
#pragma unroll
            for (int r = 0; r < 4; ++r) {
                float val = acc[i][j][r] + bc;
                if (MODE == 0) {
                    C[(size_t)(row0 + r) * N + col] = val;
                } else {
                    int row = row0 + r;
                    int b = row >> 11;          // row = b*2048 + s
                    int s = row & 2047;
                    int d = col & 127;
                    u16 o = f2bf(val);
                    if (col < 2048) {
                        int h = col >> 7;
                        qb[(((size_t)(b * 16 + h) * SEQ) + s) * 128 + d] = o;
                    } else if (col < 2560) {
                        int h = (col - 2048) >> 7;
                        kb[(((size_t)(b * 4 + h) * SEQ) + s) * 128 + d] = o;
                    } else {
                        int h = (col - 2560) >> 7;
                        vt[(((size_t)(b * 4 + h) * 128) + d) * SEQ + s] = o;  // V^T
                    }
                }
            }
        }
    }
}

// ---------------------------------------------------------------- RoPE in-place on q and k
__global__ void rope_inplace(u16* __restrict__ qb, u16* __restrict__ kb,
                             const float* __restrict__ cosb, const float* __restrict__ sinb)
{
    const int n = (65536 + 16384) * 64;
    int i = blockIdx.x * blockDim.x + threadIdx.x;
    if (i >= n) return;
    int d0  = i & 63;
    int row = i >> 6;
    u16* base;
    if (row < 65536) base = qb + (size_t)row * 128;
    else             base = kb + (size_t)(row - 65536) * 128;
    int s = row & (SEQ - 1);
    float c  = cosb[s * 128 + d0];
    float sn = sinb[s * 128 + d0];
    float a0 = bf2f(base[d0]);
    float a1 = bf2f(base[d0 + 64]);
    base[d0]      = f2bf(a0 * c - a1 * sn);
    base[d0 + 64] = f2bf(a1 * c + a0 * sn);
}

// ---------------------------------------------------------------- MFMA flash attention v4
// grid (16 [pair], 16 [h], 2 [b]); 256 threads = 4 waves; 2 blocks/CU (72KB LDS).
// Block handles q-tiles qA=pair, qB=31-pair (uniform 33 tile-halves of compute).
// v4: 64-col k-tiles, DOUBLE-BUFFERED K/V with counted vmcnt (T3/T4 2-phase pipeline):
//   issue stage(t+1) -> s_waitcnt vmcnt(8) (tile t ready, t+1 stays in flight across
//   the barrier) -> raw s_barrier -> compute -> raw s_barrier.  Never vmcnt(0) in loop.
// s_setprio(1) around MFMA clusters (T5).
// A/B share every K/V fragment read. No-max softmax: p=exp2(s_pre-scaled), l+=p.
// P transpose via per-wave rotation-swizzled [16][64] half-buffer (2-way b16 writes, free).
__global__ __launch_bounds__(256, 2) void attn_mfma(
    const u16* __restrict__ qb, const u16* __restrict__ kb,
    const u16* __restrict__ vt, u16* __restrict__ ob)
{
    __shared__ __align__(16) u16 Ks[2][4][64][32];    // 2x16KB: [buf][d-chunk][kcol][32]
    __shared__ __align__(16) u16 Vts[2][2][128][32];  // 2x16KB: [buf][kcol-chunk][d][32]
    __shared__ __align__(16) u16 Ph[4][16][64];       // 8KB: per-wave rot-swizzled P

    const int pair = blockIdx.x;
    const int qA   = pair, qB = 31 - pair;
    const int h    = blockIdx.y;
    const int b    = blockIdx.z;
    const int kvh  = h >> 2;
    const int tid  = threadIdx.x;
    const int lane = tid & 63;
    const int w    = tid >> 6;
    const int c16  = lane & 15;
    const int quad = lane >> 4;
    const float qscale = 0.08838834764831845f * 1.4426950408889634f; // 1/sqrt(128)*log2(e)

    const u16* kbase  = kb + ((size_t)(b * 4 + kvh) * SEQ) * 128;
    const u16* vtbase = vt + ((size_t)(b * 4 + kvh) * 128) * SEQ;

    // Q A-frags in registers, pre-scaled: A[m=c16][k=quad*8+e]
    bf16x8 qfA[4], qfB[4];
    {
        const u16* qpA = qb + (((size_t)(b * 16 + h)) * SEQ + qA * 64 + w * 16 + c16) * 128;
        const u16* qpB = qb + (((size_t)(b * 16 + h)) * SEQ + qB * 64 + w * 16 + c16) * 128;
#pragma unroll
        for (int kk = 0; kk < 4; ++kk) {
            bf16x8 ta = *(const bf16x8*)(qpA + kk * 32 + quad * 8);
            bf16x8 tb = *(const bf16x8*)(qpB + kk * 32 + quad * 8);
#pragma unroll
            for (int e = 0; e < 8; ++e) {
                ta[e] = (__bf16)((float)ta[e] * qscale);
                tb[e] = (__bf16)((float)tb[e] * qscale);
            }
            qfA[kk] = ta; qfB[kk] = tb;
        }
    }

    // staging source offsets (u16 units into a 16KB tile); 16 chunks of 1KB over 4 waves
    int ksrc[4], vsrc[4];
#pragma unroll
    for (int it = 0; it < 4; ++it) {
        int o  = (it * 4 + w) * 1024 + lane * 16;   // physical byte offset in 16KB tile
        int kk = o >> 12;                            // K panel (d-chunk)
        int r  = (o >> 6) & 63;                      // kcol
        int c  = (o >> 4) & 3;                       // 16B chunk in row
        ksrc[it] = r * 128 + kk * 32 + c * 8;
        int p2 = o >> 13;                            // V panel (kcol-chunk)
        int d  = (o >> 6) & 127;                     // d
        vsrc[it] = d * SEQ + p2 * 32 + c * 8;
    }

    const int nB = qB + 1;                  // 64-col k-tiles needed by qB (>= qA+1 always)
    const int rowLA = qA * 64 + w * 16 + quad * 4;
    const int rowLB = qB * 64 + w * 16 + quad * 4;

    f32x4 oA[8] = {}, oB[8] = {};
    float lA[4] = {}, lB[4] = {};

    u16* KsF  = &Ks[0][0][0][0];
    u16* VtsF = &Vts[0][0][0][0];

    // drain Q-loads so manual vmcnt counting below is exact
    asm volatile("s_waitcnt vmcnt(0)" ::: "memory");

    // prologue: stage tile 0 -> buf 0 (8 gl_lds16 per wave)
#pragma unroll
    for (int it = 0; it < 4; ++it) {
        gl_lds16(kbase  + ksrc[it], KsF  + (it * 4 + w) * 512);
        gl_lds16(vtbase + vsrc[it], VtsF + (it * 4 + w) * 512);
    }

    for (int kt = 0; kt < nB; ++kt) {
        const int cur = kt & 1;
        if (kt + 1 < nB) {
            const u16* kg = kbase  + (size_t)(kt + 1) * (64 * 128);
            const u16* vg = vtbase + (kt + 1) * 64;
            u16* kd = KsF  + ((kt + 1) & 1) * (4 * 64 * 32);
            u16* vd = VtsF + ((kt + 1) & 1) * (2 * 128 * 32);
#pragma unroll
            for (int it = 0; it < 4; ++it) {
                gl_lds16(kg + ksrc[it], kd + (it * 4 + w) * 512);
                gl_lds16(vg + vsrc[it], vd + (it * 4 + w) * 512);
            }
            asm volatile("s_waitcnt vmcnt(8)" ::: "memory"); // tile kt landed; kt+1 in flight
        } else {
            asm volatile("s_waitcnt vmcnt(0)" ::: "memory"); // last tile: full drain
        }
        __builtin_amdgcn_s_barrier();
        asm volatile("" ::: "memory");

        const u16* Kb = KsF  + cur * (4 * 64 * 32);
        const u16* Vb = VtsF + cur * (2 * 128 * 32);
        const bool doA = kt <= qA;

        f32x4 sA[4] = {}, sB[4] = {};
        __builtin_amdgcn_s_setprio(1);
        if (doA) {
#pragma unroll
            for (int kk = 0; kk < 4; ++kk)
#pragma unroll
                for (int j = 0; j < 4; ++j) {
                    bf16x8 kf = *(const bf16x8*)(Kb + (size_t)(kk * 64 + j * 16 + c16) * 32 + quad * 8);
                    sA[j] = __builtin_amdgcn_mfma_f32_16x16x32_bf16(qfA[kk], kf, sA[j], 0, 0, 0);
                    sB[j] = __builtin_amdgcn_mfma_f32_16x16x32_bf16(qfB[kk], kf, sB[j], 0, 0, 0);
                }
        } else {
#pragma unroll
            for (int kk = 0; kk < 4; ++kk)
#pragma unroll
                for (int j = 0; j < 4; ++j) {
                    bf16x8 kf = *(const bf16x8*)(Kb + (size_t)(kk * 64 + j * 16 + c16) * 32 + quad * 8);
                    sB[j] = __builtin_amdgcn_mfma_f32_16x16x32_bf16(qfB[kk], kf, sB[j], 0, 0, 0);
                }
        }
        __builtin_amdgcn_s_setprio(0);

        if (doA && kt == qA) {
#pragma unroll
            for (int j = 0; j < 4; ++j)
#pragma unroll
                for (int rr = 0; rr < 4; ++rr)
                    if (kt * 64 + j * 16 + c16 > rowLA + rr) sA[j][rr] = -1e30f;
        }
        if (kt == qB) {
#pragma unroll
            for (int j = 0; j < 4; ++j)
#pragma unroll
                for (int rr = 0; rr < 4; ++rr)
                    if (kt * 64 + j * 16 + c16 > rowLB + rr) sB[j][rr] = -1e30f;
        }

        // exp2 -> P half-buffer -> A-frags (V-frags shared A/B in PV)
        bf16x8 paA[2], paB[2];
        if (doA) {
#pragma unroll
            for (int jj = 0; jj < 4; ++jj)
#pragma unroll
                for (int rr = 0; rr < 4; ++rr) {
                    float p = __builtin_amdgcn_exp2f(sA[jj][rr]);
                    lA[rr] += p;
                    int row = quad * 4 + rr;
                    Ph[w][row][(((jj * 2 + (c16 >> 3)) + row) & 7) * 8 + (c16 & 7)] = f2bf(p);
                }
#pragma unroll
            for (int k2 = 0; k2 < 2; ++k2)
                paA[k2] = *(const bf16x8*)&Ph[w][c16][(((k2 * 4 + quad) + c16) & 7) * 8];
        }
#pragma unroll
        for (int jj = 0; jj < 4; ++jj)
#pragma unroll
            for (int rr = 0; rr < 4; ++rr) {
                float p = __builtin_amdgcn_exp2f(sB[jj][rr]);
                lB[rr] += p;
                int row = quad * 4 + rr;
                Ph[w][row][(((jj * 2 + (c16 >> 3)) + row) & 7) * 8 + (c16 & 7)] = f2bf(p);
            }
#pragma unroll
        for (int k2 = 0; k2 < 2; ++k2)
            paB[k2] = *(const bf16x8*)&Ph[w][c16][(((k2 * 4 + quad) + c16) & 7) * 8];

        __builtin_amdgcn_s_setprio(1);
        if (doA) {
#pragma unroll
            for (int k2 = 0; k2 < 2; ++k2)
#pragma unroll
                for (int nt = 0; nt < 8; ++nt) {
                    bf16x8 vf = *(const bf16x8*)(Vb + (size_t)(k2 * 128 + nt * 16 + c16) * 32 + quad * 8);
                    oA[nt] = __builtin_amdgcn_mfma_f32_16x16x32_bf16(paA[k2], vf, oA[nt], 0, 0, 0);
                    oB[nt] = __builtin_amdgcn_mfma_f32_16x16x32_bf16(paB[k2], vf, oB[nt], 0, 0, 0);
                }
        } else {
#pragma unroll
            for (int k2 = 0; k2 < 2; ++k2)
#pragma unroll
                for (int nt = 0; nt < 8; ++nt) {
                    bf16x8 vf = *(const bf16x8*)(Vb + (size_t)(k2 * 128 + nt * 16 + c16) * 32 + quad * 8);
                    oB[nt] = __builtin_amdgcn_mfma_f32_16x16x32_bf16(paB[k2], vf, oB[nt], 0, 0, 0);
                }
        }
        __builtin_amdgcn_s_setprio(0);

        asm volatile("" ::: "memory");
        __builtin_amdgcn_s_barrier();
    }

    // epilogue: row-sum of l across the 16-lane col groups, normalize, store
    float liA[4], liB[4];
#pragma unroll
    for (int rr = 0; rr < 4; ++rr) {
        float la = lA[rr], lb = lB[rr];
        la += __shfl_xor(la, 1); lb += __shfl_xor(lb, 1);
        la += __shfl_xor(la, 2); lb += __shfl_xor(lb, 2);
        la += __shfl_xor(la, 4); lb += __shfl_xor(lb, 4);
        la += __shfl_xor(la, 8); lb += __shfl_xor(lb, 8);
        liA[rr] = 1.0f / la;     liB[rr] = 1.0f / lb;
    }
    const size_t rowGA = (size_t)b * SEQ + rowLA;
    const size_t rowGB = (size_t)b * SEQ + rowLB;
#pragma unroll
    for (int nt = 0; nt < 8; ++nt)
#pragma unroll
        for (int rr = 0; rr < 4; ++rr) {
            ob[(rowGA + rr) * 2048 + h * 128 + nt * 16 + c16] = f2bf(oA[nt][rr] * liA[rr]);
            ob[(rowGB + rr) * 2048 + h * 128 + nt * 16 + c16] = f2bf(oB[nt][rr] * liB[rr]);
        }
}

// ---------------------------------------------------------------- launch
extern "C" void kernel_launch(void* const* d_in, const int* in_sizes, int n_in,
                              void* d_out, int out_size, void* d_ws, size_t ws_size,
                              hipStream_t stream) {
    const float* x    = (const float*)d_in[0];
    const float* wq   = (const float*)d_in[1];
    const float* bq   = (const float*)d_in[2];
    const float* wk   = (const float*)d_in[3];
    const float* bk   = (const float*)d_in[4];
    const float* wv   = (const float*)d_in[5];
    const float* bv   = (const float*)d_in[6];
    const float* wo   = (const float*)d_in[7];
    const float* bo   = (const float*)d_in[8];
    const float* cosb = (const float*)d_in[9];
    const float* sinb = (const float*)d_in[10];
    float* out = (float*)d_out;

    char* ws = (char*)d_ws;
    // workspace layout (bytes); total ~52 MB (validated r2-r4)
    const size_t OFF_WQKV = 0;              // 12,582,912  packed [wq|wk|wv] bf16; later wo bf16
    const size_t OFF_BIAS = 12582912;       //     16,384  packed qkv bias f32
    const size_t OFF_QB   = 12599296;       // 16,777,216  q bf16 (B,16,S,128)
    const size_t OFF_KB   = 29376512;       //  4,194,304  k bf16 (B,4,S,128)
    const size_t OFF_VT   = 33570816;       //  4,194,304  v^T bf16 (B,4,128,S)
    const size_t OFF_XB   = 37765120;       // 16,777,216  x bf16; later attn out bf16

    u16*   wqkvb = (u16*)(ws + OFF_WQKV);
    u16*   wob   = (u16*)(ws + OFF_WQKV);   // reuse after GEMM1
    float* biasb = (float*)(ws + OFF_BIAS);
    u16*   qb2   = (u16*)(ws + OFF_QB);
    u16*   kb2   = (u16*)(ws + OFF_KB);
    u16*   vt2   = (u16*)(ws + OFF_VT);
    u16*   xb    = (u16*)(ws + OFF_XB);
    u16*   attnb = (u16*)(ws + OFF_XB);     // reuse after GEMM1

    // 1. fused prep: x->bf16, wq/wk/wv->bf16 packed, bias pack
    prep<<<4096, 256, 0, stream>>>(x, wq, wk, wv, bq, bk, bv, xb, wqkvb, biasb);

    // 2. qkv = x @ [wq|wk|wv]^T + bias, split-written bf16: q,k natural; v transposed
    gemm_bt<1><<<dim3(32, 24), 256, 0, stream>>>(xb, wqkvb, biasb, nullptr,
                                                 qb2, kb2, vt2, 4096, 3072, 2048);

    // 3. wo -> bf16 (reuses wqkv region; stream-ordered after GEMM1)
    cvt_f32_bf16<<<4096, 256, 0, stream>>>(wo, wob, 1048576);

    // 4. RoPE in-place on q and k
    rope_inplace<<<((65536 + 16384) * 64) / 256, 256, 0, stream>>>(qb2, kb2, cosb, sinb);

    // 5. causal GQA MFMA attention v4 -> (B*S, 2048) bf16
    attn_mfma<<<dim3(16, 16, 2), 256, 0, stream>>>(qb2, kb2, vt2, attnb);

    // 6. out = attn @ wo^T + bo  (fp32 to d_out)
    gemm_bt<0><<<dim3(32, 16), 256, 0, stream>>>(attnb, wob, bo, out,
                                                 nullptr, nullptr, nullptr, 4096, 2048, 2048);
}

// Round 4
// 351.813 us; speedup vs baseline: 1.0741x; 1.0741x over previous
//
#include <hip/hip_runtime.h>

typedef unsigned short u16;
typedef __bf16 bf16x8 __attribute__((ext_vector_type(8)));
typedef float  f32x4  __attribute__((ext_vector_type(4)));

#define SEQ 2048

__device__ __forceinline__ float bf2f(u16 u) {
    union { unsigned int i; float f; } c;
    c.i = ((unsigned int)u) << 16;
    return c.f;
}
__device__ __forceinline__ u16 f2bf(float f) {
    union { float f; unsigned int i; } c;
    c.f = f;
    unsigned int u = c.i;
    u += 0x7FFFu + ((u >> 16) & 1u);   // round-to-nearest-even
    return (u16)(u >> 16);
}

// async global->LDS, 16B per lane; lds dest = wave-uniform base + lane*16
__device__ __forceinline__ void gl_lds16(const u16* g, u16* l) {
    __builtin_amdgcn_global_load_lds(
        (const __attribute__((address_space(1))) unsigned int*)(g),
        (__attribute__((address_space(3))) unsigned int*)(l), 16, 0, 0);
}

__device__ __forceinline__ void cvt4(const float* s, u16* d) {
    float4 v = *(const float4*)s;
    ushort4 o;
    o.x = f2bf(v.x); o.y = f2bf(v.y); o.z = f2bf(v.z); o.w = f2bf(v.w);
    *(ushort4*)d = o;
}

// ---------------------------------------------------------------- fused prep
__global__ void prep(const float* __restrict__ x,
                     const float* __restrict__ wq, const float* __restrict__ wk,
                     const float* __restrict__ wv,
                     const float* __restrict__ bq, const float* __restrict__ bk,
                     const float* __restrict__ bv,
                     u16* __restrict__ xb, u16* __restrict__ wqkvb,
                     float* __restrict__ biasb)
{
    const int E0 = 2097152;            // x float4s
    const int E1 = E0 + 1048576;       // wq
    const int E2 = E1 + 262144;        // wk
    const int E3 = E2 + 262144;        // wv
    const int E4 = E3 + 768;           // bias float4s
    int i = blockIdx.x * blockDim.x + threadIdx.x;
    int stride = gridDim.x * blockDim.x;
    for (; i < E4; i += stride) {
        if (i < E0)      cvt4(x  + (size_t)i * 4,        xb    + (size_t)i * 4);
        else if (i < E1) cvt4(wq + (size_t)(i - E0) * 4, wqkvb + (size_t)(i - E0) * 4);
        else if (i < E2) cvt4(wk + (size_t)(i - E1) * 4, wqkvb + 4194304 + (size_t)(i - E1) * 4);
        else if (i < E3) cvt4(wv + (size_t)(i - E2) * 4, wqkvb + 5242880 + (size_t)(i - E2) * 4);
        else {
            int j = i - E3;            // 0..767
            const float* src = (j < 512) ? (bq + j * 4)
                             : (j < 640) ? (bk + (j - 512) * 4)
                                         : (bv + (j - 640) * 4);
            *(float4*)&biasb[j * 4] = *(const float4*)src;
        }
    }
}

__global__ void cvt_f32_bf16(const float* __restrict__ in, u16* __restrict__ out, int n4) {
    int i = blockIdx.x * blockDim.x + threadIdx.x;
    int stride = gridDim.x * blockDim.x;
    for (; i < n4; i += stride) cvt4(in + (size_t)i * 4, out + (size_t)i * 4);
}

// ---------------------------------------------------------------- GEMM C = A*B^T + bias
// global_load_lds staging (m97 pattern), plain layout.
// MODE 0: C fp32. MODE 1: qkv split q/k natural (B,H,S,128), v transposed (B,4,128,S).
template<int MODE>
__global__ __launch_bounds__(256) void gemm_bt(
    const u16* __restrict__ A, const u16* __restrict__ B,
    const float* __restrict__ bias, float* __restrict__ C,
    u16* __restrict__ qb, u16* __restrict__ kb, u16* __restrict__ vt,
    int M, int N, int K)
{
    __shared__ __align__(16) u16 lA[128 * 32];
    __shared__ __align__(16) u16 lB[128 * 32];
    const int tid   = threadIdx.x;
    const int lane  = tid & 63;
    const int wave  = tid >> 6;
    const int waveM = (wave >> 1) * 64;
    const int waveN = (wave & 1) * 64;
    const int bm = blockIdx.x * 128;
    const int bn = blockIdx.y * 128;
    const int lrow = lane & 15;
    const int koff = (lane >> 4) * 8;

    f32x4 acc[4][4] = {};

    for (int k0 = 0; k0 < K; k0 += 32) {
        __syncthreads();
#pragma unroll
        for (int p = 0; p < 2; ++p) {
            int idx = p * 256 + tid;    // 0..511
            int row = idx >> 2;         // 0..127
            int ch  = idx & 3;          // 16B chunk
            gl_lds16(&A[(size_t)(bm + row) * K + k0 + ch * 8], &lA[(p * 256 + wave * 64) * 8]);
            gl_lds16(&B[(size_t)(bn + row) * K + k0 + ch * 8], &lB[(p * 256 + wave * 64) * 8]);
        }
        __syncthreads();

        bf16x8 af[4], bfr[4];
#pragma unroll
        for (int i = 0; i < 4; ++i)
            af[i] = *(const bf16x8*)&lA[(waveM + i * 16 + lrow) * 32 + koff];
#pragma unroll
        for (int j = 0; j < 4; ++j)
            bfr[j] = *(const bf16x8*)&lB[(waveN + j * 16 + lrow) * 32 + koff];
#pragma unroll
        for (int i = 0; i < 4; ++i)
#pragma unroll
            for (int j = 0; j < 4; ++j)
                acc[i][j] = __builtin_amdgcn_mfma_f32_16x16x32_bf16(
                    af[i], bfr[j], acc[i][j], 0, 0, 0);
    }

    const int r4 = (lane >> 4) * 4;
    const int cn = lane & 15;
#pragma unroll
    for (int i = 0; i < 4; ++i) {
#pragma unroll
        for (int j = 0; j < 4; ++j) {
            int row0 = bm + waveM + i * 16 + r4;
            int col  = bn + waveN + j * 16 + cn;
            float bc = bias[col];
#pragma unroll
            for (int r = 0; r < 4; ++r) {
                float val = acc[i][j][r] + bc;
                if (MODE == 0) {
                    C[(size_t)(row0 + r) * N + col] = val;
                } else {
                    int row = row0 + r;
                    int b = row >> 11;          // row = b*2048 + s
                    int s = row & 2047;
                    int d = col & 127;
                    u16 o = f2bf(val);
                    if (col < 2048) {
                        int h = col >> 7;
                        qb[(((size_t)(b * 16 + h) * SEQ) + s) * 128 + d] = o;
                    } else if (col < 2560) {
                        int h = (col - 2048) >> 7;
                        kb[(((size_t)(b * 4 + h) * SEQ) + s) * 128 + d] = o;
                    } else {
                        int h = (col - 2560) >> 7;
                        vt[(((size_t)(b * 4 + h) * 128) + d) * SEQ + s] = o;  // V^T
                    }
                }
            }
        }
    }
}

// ---------------------------------------------------------------- RoPE in-place on q and k
__global__ void rope_inplace(u16* __restrict__ qb, u16* __restrict__ kb,
                             const float* __restrict__ cosb, const float* __restrict__ sinb)
{
    const int n = (65536 + 16384) * 64;
    int i = blockIdx.x * blockDim.x + threadIdx.x;
    if (i >= n) return;
    int d0  = i & 63;
    int row = i >> 6;
    u16* base;
    if (row < 65536) base = qb + (size_t)row * 128;
    else             base = kb + (size_t)(row - 65536) * 128;
    int s = row & (SEQ - 1);
    float c  = cosb[s * 128 + d0];
    float sn = sinb[s * 128 + d0];
    float a0 = bf2f(base[d0]);
    float a1 = bf2f(base[d0 + 64]);
    base[d0]      = f2bf(a0 * c - a1 * sn);
    base[d0 + 64] = f2bf(a1 * c + a0 * sn);
}

// ---------------------------------------------------------------- MFMA flash attention v5
// v5 = v3 structure (proven 89us; single-buffered 128-col tiles, 2-barrier loop) +
//   (1) XCD slice swizzle: flat grid 512, id&7 = (b,kvh) slice -> under round-robin
//       XCD dispatch each XCD serves ONE 1MB K/V slice from its own L2 (was: every
//       XCD touched all 8 slices = 8MB > 4MB L2 -> thrash, FETCH 42MB vs 25MB ideal).
//   (2) native (__bf16) casts in the softmax hot path (1 cvt vs 5-op manual f2bf).
// v4's counted-vmcnt 2-phase graft regressed (115us) per m196's warning - reverted.
__global__ __launch_bounds__(256, 2) void attn_mfma(
    const u16* __restrict__ qb, const u16* __restrict__ kb,
    const u16* __restrict__ vt, u16* __restrict__ ob)
{
    __shared__ __align__(16) u16 Ks[4][128][32];    // 32KB: [d-chunk][kcol][32]
    __shared__ __align__(16) u16 Vts[4][128][32];   // 32KB: [kcol-chunk][d][32]
    __shared__ __align__(16) u16 Ph[4][16][64];     // 8KB: per-wave rot-swizzled P half

    // flat-grid decode: id&7 = (b,kvh) slice (XCD-pinned), id>>3 = (pair, h_lo)
    const int id   = blockIdx.x;
    const int s8   = id & 7;
    const int n    = id >> 3;          // 0..63
    const int pair = n & 15;
    const int h_lo = n >> 4;           // 0..3
    const int b    = s8 >> 2;
    const int kvh  = s8 & 3;
    const int h    = kvh * 4 + h_lo;
    const int qA   = pair, qB = 31 - pair;

    const int tid  = threadIdx.x;
    const int lane = tid & 63;
    const int w    = tid >> 6;
    const int c16  = lane & 15;
    const int quad = lane >> 4;
    const float qscale = 0.08838834764831845f * 1.4426950408889634f; // 1/sqrt(128)*log2(e)

    const u16* kbase  = kb + ((size_t)(b * 4 + kvh) * SEQ) * 128;
    const u16* vtbase = vt + ((size_t)(b * 4 + kvh) * 128) * SEQ;

    // Q A-frags in registers, pre-scaled: A[m=c16][k=quad*8+e]
    bf16x8 qfA[4], qfB[4];
    {
        const u16* qpA = qb + (((size_t)(b * 16 + h)) * SEQ + qA * 64 + w * 16 + c16) * 128;
        const u16* qpB = qb + (((size_t)(b * 16 + h)) * SEQ + qB * 64 + w * 16 + c16) * 128;
#pragma unroll
        for (int kk = 0; kk < 4; ++kk) {
            bf16x8 ta = *(const bf16x8*)(qpA + kk * 32 + quad * 8);
            bf16x8 tb = *(const bf16x8*)(qpB + kk * 32 + quad * 8);
#pragma unroll
            for (int e = 0; e < 8; ++e) {
                ta[e] = (__bf16)((float)ta[e] * qscale);
                tb[e] = (__bf16)((float)tb[e] * qscale);
            }
            qfA[kk] = ta; qfB[kk] = tb;
        }
    }

    // staging source offsets (u16 units into the tile); 32 chunks of 1KB over 4 waves
    int ksrc[8], vsrc[8];
#pragma unroll
    for (int it = 0; it < 8; ++it) {
        int o  = (it * 4 + w) * 1024 + lane * 16;   // physical byte offset in 32KB region
        int kk = o >> 13;                            // panel
        int r  = (o >> 6) & 127;                     // kcol (K) / d (V^T)
        int c  = (o >> 4) & 3;                       // 16B chunk in row
        ksrc[it] = r * 128 + kk * 32 + c * 8;
        vsrc[it] = r * SEQ + kk * 32 + c * 8;
    }

    const int nA = (qA + 2) >> 1;        // k-tiles needed by qA
    const int nB = (qB + 2) >> 1;        // >= nA always
    const int rowLA = qA * 64 + w * 16 + quad * 4;
    const int rowLB = qB * 64 + w * 16 + quad * 4;

    f32x4 oA[8] = {}, oB[8] = {};
    float lA[4] = {}, lB[4] = {};

    u16* KsF  = &Ks[0][0][0];
    u16* VtsF = &Vts[0][0][0];

    for (int kt = 0; kt < nB; ++kt) {
        __syncthreads();                            // all waves done with prev K/V
        const u16* kg = kbase + (size_t)kt * (128 * 128);
        const u16* vg = vtbase + kt * 128;
#pragma unroll
        for (int it = 0; it < 8; ++it) {
            gl_lds16(kg + ksrc[it], &KsF[(it * 4 + w) * 512]);
            gl_lds16(vg + vsrc[it], &VtsF[(it * 4 + w) * 512]);
        }
        __syncthreads();                            // drains DMA (vmcnt)

        const bool doA = kt < nA;
        f32x4 sA[8] = {}, sB[8] = {};
        if (doA) {
#pragma unroll
            for (int kk = 0; kk < 4; ++kk)
#pragma unroll
                for (int j = 0; j < 8; ++j) {
                    bf16x8 kf = *(const bf16x8*)&Ks[kk][j * 16 + c16][quad * 8];
                    sA[j] = __builtin_amdgcn_mfma_f32_16x16x32_bf16(qfA[kk], kf, sA[j], 0, 0, 0);
                    sB[j] = __builtin_amdgcn_mfma_f32_16x16x32_bf16(qfB[kk], kf, sB[j], 0, 0, 0);
                }
        } else {
#pragma unroll
            for (int kk = 0; kk < 4; ++kk)
#pragma unroll
                for (int j = 0; j < 8; ++j) {
                    bf16x8 kf = *(const bf16x8*)&Ks[kk][j * 16 + c16][quad * 8];
                    sB[j] = __builtin_amdgcn_mfma_f32_16x16x32_bf16(qfB[kk], kf, sB[j], 0, 0, 0);
                }
        }

        if (doA && kt == nA - 1) {
#pragma unroll
            for (int j = 0; j < 8; ++j)
#pragma unroll
                for (int rr = 0; rr < 4; ++rr)
                    if (kt * 128 + j * 16 + c16 > rowLA + rr) sA[j][rr] = -1e30f;
        }
        if (kt == nB - 1) {
#pragma unroll
            for (int j = 0; j < 8; ++j)
#pragma unroll
                for (int rr = 0; rr < 4; ++rr)
                    if (kt * 128 + j * 16 + c16 > rowLB + rr) sB[j][rr] = -1e30f;
        }

        // two 64-col halves: exp2 -> P half-buffer -> A-frags -> PV (V-frags shared A/B)
#pragma unroll
        for (int hf = 0; hf < 2; ++hf) {
            bf16x8 paA[2], paB[2];
            if (doA) {
#pragma unroll
                for (int jj = 0; jj < 4; ++jj) {
                    int j = hf * 4 + jj;
#pragma unroll
                    for (int rr = 0; rr < 4; ++rr) {
                        float p = __builtin_amdgcn_exp2f(sA[j][rr]);
                        lA[rr] += p;
                        int row = quad * 4 + rr;
                        *(__bf16*)&Ph[w][row][(((jj * 2 + (c16 >> 3)) + row) & 7) * 8 + (c16 & 7)] = (__bf16)p;
                    }
                }
#pragma unroll
                for (int k2 = 0; k2 < 2; ++k2)
                    paA[k2] = *(const bf16x8*)&Ph[w][c16][(((k2 * 4 + quad) + c16) & 7) * 8];
            }
#pragma unroll
            for (int jj = 0; jj < 4; ++jj) {
                int j = hf * 4 + jj;
#pragma unroll
                for (int rr = 0; rr < 4; ++rr) {
                    float p = __builtin_amdgcn_exp2f(sB[j][rr]);
                    lB[rr] += p;
                    int row = quad * 4 + rr;
                    *(__bf16*)&Ph[w][row][(((jj * 2 + (c16 >> 3)) + row) & 7) * 8 + (c16 & 7)] = (__bf16)p;
                }
            }
#pragma unroll
            for (int k2 = 0; k2 < 2; ++k2)
                paB[k2] = *(const bf16x8*)&Ph[w][c16][(((k2 * 4 + quad) + c16) & 7) * 8];

            if (doA) {
#pragma unroll
                for (int k2 = 0; k2 < 2; ++k2)
#pragma unroll
                    for (int nt = 0; nt < 8; ++nt) {
                        bf16x8 vf = *(const bf16x8*)&Vts[hf * 2 + k2][nt * 16 + c16][quad * 8];
                        oA[nt] = __builtin_amdgcn_mfma_f32_16x16x32_bf16(paA[k2], vf, oA[nt], 0, 0, 0);
                        oB[nt] = __builtin_amdgcn_mfma_f32_16x16x32_bf16(paB[k2], vf, oB[nt], 0, 0, 0);
                    }
            } else {
#pragma unroll
                for (int k2 = 0; k2 < 2; ++k2)
#pragma unroll
                    for (int nt = 0; nt < 8; ++nt) {
                        bf16x8 vf = *(const bf16x8*)&Vts[hf * 2 + k2][nt * 16 + c16][quad * 8];
                        oB[nt] = __builtin_amdgcn_mfma_f32_16x16x32_bf16(paB[k2], vf, oB[nt], 0, 0, 0);
                    }
            }
        }
    }

    // epilogue: row-sum of l across the 16-lane col groups, normalize, store
    float liA[4], liB[4];
#pragma unroll
    for (int rr = 0; rr < 4; ++rr) {
        float la = lA[rr], lb = lB[rr];
        la += __shfl_xor(la, 1); lb += __shfl_xor(lb, 1);
        la += __shfl_xor(la, 2); lb += __shfl_xor(lb, 2);
        la += __shfl_xor(la, 4); lb += __shfl_xor(lb, 4);
        la += __shfl_xor(la, 8); lb += __shfl_xor(lb, 8);
        liA[rr] = 1.0f / la;     liB[rr] = 1.0f / lb;
    }
    const size_t rowGA = (size_t)b * SEQ + rowLA;
    const size_t rowGB = (size_t)b * SEQ + rowLB;
#pragma unroll
    for (int nt = 0; nt < 8; ++nt)
#pragma unroll
        for (int rr = 0; rr < 4; ++rr) {
            ob[(rowGA + rr) * 2048 + h * 128 + nt * 16 + c16] = f2bf(oA[nt][rr] * liA[rr]);
            ob[(rowGB + rr) * 2048 + h * 128 + nt * 16 + c16] = f2bf(oB[nt][rr] * liB[rr]);
        }
}

// ---------------------------------------------------------------- launch
extern "C" void kernel_launch(void* const* d_in, const int* in_sizes, int n_in,
                              void* d_out, int out_size, void* d_ws, size_t ws_size,
                              hipStream_t stream) {
    const float* x    = (const float*)d_in[0];
    const float* wq   = (const float*)d_in[1];
    const float* bq   = (const float*)d_in[2];
    const float* wk   = (const float*)d_in[3];
    const float* bk   = (const float*)d_in[4];
    const float* wv   = (const float*)d_in[5];
    const float* bv   = (const float*)d_in[6];
    const float* wo   = (const float*)d_in[7];
    const float* bo   = (const float*)d_in[8];
    const float* cosb = (const float*)d_in[9];
    const float* sinb = (const float*)d_in[10];
    float* out = (float*)d_out;

    char* ws = (char*)d_ws;
    // workspace layout (bytes); total ~52 MB (validated r2-r4)
    const size_t OFF_WQKV = 0;              // 12,582,912  packed [wq|wk|wv] bf16; later wo bf16
    const size_t OFF_BIAS = 12582912;       //     16,384  packed qkv bias f32
    const size_t OFF_QB   = 12599296;       // 16,777,216  q bf16 (B,16,S,128)
    const size_t OFF_KB   = 29376512;       //  4,194,304  k bf16 (B,4,S,128)
    const size_t OFF_VT   = 33570816;       //  4,194,304  v^T bf16 (B,4,128,S)
    const size_t OFF_XB   = 37765120;       // 16,777,216  x bf16; later attn out bf16

    u16*   wqkvb = (u16*)(ws + OFF_WQKV);
    u16*   wob   = (u16*)(ws + OFF_WQKV);   // reuse after GEMM1
    float* biasb = (float*)(ws + OFF_BIAS);
    u16*   qb2   = (u16*)(ws + OFF_QB);
    u16*   kb2   = (u16*)(ws + OFF_KB);
    u16*   vt2   = (u16*)(ws + OFF_VT);
    u16*   xb    = (u16*)(ws + OFF_XB);
    u16*   attnb = (u16*)(ws + OFF_XB);     // reuse after GEMM1

    // 1. fused prep: x->bf16, wq/wk/wv->bf16 packed, bias pack
    prep<<<4096, 256, 0, stream>>>(x, wq, wk, wv, bq, bk, bv, xb, wqkvb, biasb);

    // 2. qkv = x @ [wq|wk|wv]^T + bias, split-written bf16: q,k natural; v transposed
    gemm_bt<1><<<dim3(32, 24), 256, 0, stream>>>(xb, wqkvb, biasb, nullptr,
                                                 qb2, kb2, vt2, 4096, 3072, 2048);

    // 3. wo -> bf16 (reuses wqkv region; stream-ordered after GEMM1)
    cvt_f32_bf16<<<4096, 256, 0, stream>>>(wo, wob, 1048576);

    // 4. RoPE in-place on q and k
    rope_inplace<<<((65536 + 16384) * 64) / 256, 256, 0, stream>>>(qb2, kb2, cosb, sinb);

    // 5. causal GQA MFMA attention v5 (flat grid, XCD slice swizzle) -> (B*S, 2048) bf16
    attn_mfma<<<512, 256, 0, stream>>>(qb2, kb2, vt2, attnb);

    // 6. out = attn @ wo^T + bo  (fp32 to d_out)
    gemm_bt<0><<<dim3(32, 16), 256, 0, stream>>>(attnb, wob, bo, out,
                                                 nullptr, nullptr, nullptr, 4096, 2048, 2048);
}

// Round 5
// 347.266 us; speedup vs baseline: 1.0882x; 1.0131x over previous
//
#include <hip/hip_runtime.h>

typedef unsigned short u16;
typedef __bf16 bf16x8 __attribute__((ext_vector_type(8)));
typedef float  f32x4  __attribute__((ext_vector_type(4)));

#define SEQ 2048

__device__ __forceinline__ float bf2f(u16 u) {
    union { unsigned int i; float f; } c;
    c.i = ((unsigned int)u) << 16;
    return c.f;
}
__device__ __forceinline__ u16 f2bf(float f) {
    union { float f; unsigned int i; } c;
    c.f = f;
    unsigned int u = c.i;
    u += 0x7FFFu + ((u >> 16) & 1u);   // round-to-nearest-even
    return (u16)(u >> 16);
}

// async global->LDS, 16B per lane; lds dest = wave-uniform base + lane*16
__device__ __forceinline__ void gl_lds16(const u16* g, u16* l) {
    __builtin_amdgcn_global_load_lds(
        (const __attribute__((address_space(1))) unsigned int*)(g),
        (__attribute__((address_space(3))) unsigned int*)(l), 16, 0, 0);
}

__device__ __forceinline__ void cvt4(const float* s, u16* d) {
    float4 v = *(const float4*)s;
    ushort4 o;
    o.x = f2bf(v.x); o.y = f2bf(v.y); o.z = f2bf(v.z); o.w = f2bf(v.w);
    *(ushort4*)d = o;
}

// ---------------------------------------------------------------- fused prep
__global__ void prep(const float* __restrict__ x,
                     const float* __restrict__ wq, const float* __restrict__ wk,
                     const float* __restrict__ wv,
                     const float* __restrict__ bq, const float* __restrict__ bk,
                     const float* __restrict__ bv,
                     u16* __restrict__ xb, u16* __restrict__ wqkvb,
                     float* __restrict__ biasb)
{
    const int E0 = 2097152;            // x float4s
    const int E1 = E0 + 1048576;       // wq
    const int E2 = E1 + 262144;        // wk
    const int E3 = E2 + 262144;        // wv
    const int E4 = E3 + 768;           // bias float4s
    int i = blockIdx.x * blockDim.x + threadIdx.x;
    int stride = gridDim.x * blockDim.x;
    for (; i < E4; i += stride) {
        if (i < E0)      cvt4(x  + (size_t)i * 4,        xb    + (size_t)i * 4);
        else if (i < E1) cvt4(wq + (size_t)(i - E0) * 4, wqkvb + (size_t)(i - E0) * 4);
        else if (i < E2) cvt4(wk + (size_t)(i - E1) * 4, wqkvb + 4194304 + (size_t)(i - E1) * 4);
        else if (i < E3) cvt4(wv + (size_t)(i - E2) * 4, wqkvb + 5242880 + (size_t)(i - E2) * 4);
        else {
            int j = i - E3;            // 0..767
            const float* src = (j < 512) ? (bq + j * 4)
                             : (j < 640) ? (bk + (j - 512) * 4)
                                         : (bv + (j - 640) * 4);
            *(float4*)&biasb[j * 4] = *(const float4*)src;
        }
    }
}

__global__ void cvt_f32_bf16(const float* __restrict__ in, u16* __restrict__ out, int n4) {
    int i = blockIdx.x * blockDim.x + threadIdx.x;
    int stride = gridDim.x * blockDim.x;
    for (; i < n4; i += stride) cvt4(in + (size_t)i * 4, out + (size_t)i * 4);
}

// ---------------------------------------------------------------- GEMM C = A*B^T + bias
// global_load_lds staging (m97 pattern), plain layout.
// MODE 0: C fp32. MODE 1: qkv split q/k natural (B,H,S,128), v transposed (B,4,128,S).
template<int MODE>
__global__ __launch_bounds__(256) void gemm_bt(
    const u16* __restrict__ A, const u16* __restrict__ B,
    const float* __restrict__ bias, float* __restrict__ C,
    u16* __restrict__ qb, u16* __restrict__ kb, u16* __restrict__ vt,
    int M, int N, int K)
{
    __shared__ __align__(16) u16 lA[128 * 32];
    __shared__ __align__(16) u16 lB[128 * 32];
    const int tid   = threadIdx.x;
    const int lane  = tid & 63;
    const int wave  = tid >> 6;
    const int waveM = (wave >> 1) * 64;
    const int waveN = (wave & 1) * 64;
    const int bm = blockIdx.x * 128;
    const int bn = blockIdx.y * 128;
    const int lrow = lane & 15;
    const int koff = (lane >> 4) * 8;

    f32x4 acc[4][4] = {};

    for (int k0 = 0; k0 < K; k0 += 32) {
        __syncthreads();
#pragma unroll
        for (int p = 0; p < 2; ++p) {
            int idx = p * 256 + tid;    // 0..511
            int row = idx >> 2;         // 0..127
            int ch  = idx & 3;          // 16B chunk
            gl_lds16(&A[(size_t)(bm + row) * K + k0 + ch * 8], &lA[(p * 256 + wave * 64) * 8]);
            gl_lds16(&B[(size_t)(bn + row) * K + k0 + ch * 8], &lB[(p * 256 + wave * 64) * 8]);
        }
        __syncthreads();

        bf16x8 af[4], bfr[4];
#pragma unroll
        for (int i = 0; i < 4; ++i)
            af[i] = *(const bf16x8*)&lA[(waveM + i * 16 + lrow) * 32 + koff];
#pragma unroll
        for (int j = 0; j < 4; ++j)
            bfr[j] = *(const bf16x8*)&lB[(waveN + j * 16 + lrow) * 32 + koff];
#pragma unroll
        for (int i = 0; i < 4; ++i)
#pragma unroll
            for (int j = 0; j < 4; ++j)
                acc[i][j] = __builtin_amdgcn_mfma_f32_16x16x32_bf16(
                    af[i], bfr[j], acc[i][j], 0, 0, 0);
    }

    const int r4 = (lane >> 4) * 4;
    const int cn = lane & 15;
#pragma unroll
    for (int i = 0; i < 4; ++i) {
#pragma unroll
        for (int j = 0; j < 4; ++j) {
            int row0 = bm + waveM + i * 16 + r4;
            int col  = bn + waveN + j * 16 + cn;
            float bc = bias[col];
#pragma unroll
            for (int r = 0; r < 4; ++r) {
                float val = acc[i][j][r] + bc;
                if (MODE == 0) {
                    C[(size_t)(row0 + r) * N + col] = val;
                } else {
                    int row = row0 + r;
                    int b = row >> 11;          // row = b*2048 + s
                    int s = row & 2047;
                    int d = col & 127;
                    u16 o = f2bf(val);
                    if (col < 2048) {
                        int h = col >> 7;
                        qb[(((size_t)(b * 16 + h) * SEQ) + s) * 128 + d] = o;
                    } else if (col < 2560) {
                        int h = (col - 2048) >> 7;
                        kb[(((size_t)(b * 4 + h) * SEQ) + s) * 128 + d] = o;
                    } else {
                        int h = (col - 2560) >> 7;
                        vt[(((size_t)(b * 4 + h) * 128) + d) * SEQ + s] = o;  // V^T
                    }
                }
            }
        }
    }
}

// ---------------------------------------------------------------- RoPE in-place on q and k
__global__ void rope_inplace(u16* __restrict__ qb, u16* __restrict__ kb,
                             const float* __restrict__ cosb, const float* __restrict__ sinb)
{
    const int n = (65536 + 16384) * 64;
    int i = blockIdx.x * blockDim.x + threadIdx.x;
    if (i >= n) return;
    int d0  = i & 63;
    int row = i >> 6;
    u16* base;
    if (row < 65536) base = qb + (size_t)row * 128;
    else             base = kb + (size_t)(row - 65536) * 128;
    int s = row & (SEQ - 1);
    float c  = cosb[s * 128 + d0];
    float sn = sinb[s * 128 + d0];
    float a0 = bf2f(base[d0]);
    float a1 = bf2f(base[d0 + 64]);
    base[d0]      = f2bf(a0 * c - a1 * sn);
    base[d0 + 64] = f2bf(a1 * c + a0 * sn);
}

// ---------------------------------------------------------------- MFMA flash attention v6
// v6 = v5 (XCD slice swizzle: FETCH 42->19MB, proven) + intra-block overlap:
//   64-col K/V tiles, DOUBLE-BUFFERED, ONE __syncthreads per tile:
//     stage(t+1 -> buf^1); compute(buf); __syncthreads(); buf^=1;
//   The barrier's implicit vmcnt(0) drains a DMA that had the whole compute
//   phase to land -> drain ~free. No inline asm / raw barriers (v4 lesson:
//   manual vmcnt + "memory"-clobber asm regressed 30%; compiler owns the waits).
//   Barrier rate per column identical to v5 (1 per 64 cols). LDS 72KB, 2 blk/CU.
__global__ __launch_bounds__(256, 2) void attn_mfma(
    const u16* __restrict__ qb, const u16* __restrict__ kb,
    const u16* __restrict__ vt, u16* __restrict__ ob)
{
    __shared__ __align__(16) u16 Ks[2][4][64][32];    // 2x16KB: [buf][d-chunk][kcol][32]
    __shared__ __align__(16) u16 Vts[2][2][128][32];  // 2x16KB: [buf][kcol-chunk][d][32]
    __shared__ __align__(16) u16 Ph[4][16][64];       // 8KB: per-wave rot-swizzled P

    // flat-grid decode: id&7 = (b,kvh) slice (XCD-pinned), id>>3 = (pair, h_lo)
    const int id   = blockIdx.x;
    const int s8   = id & 7;
    const int n    = id >> 3;          // 0..63
    const int pair = n & 15;
    const int h_lo = n >> 4;           // 0..3
    const int b    = s8 >> 2;
    const int kvh  = s8 & 3;
    const int h    = kvh * 4 + h_lo;
    const int qA   = pair, qB = 31 - pair;

    const int tid  = threadIdx.x;
    const int lane = tid & 63;
    const int w    = tid >> 6;
    const int c16  = lane & 15;
    const int quad = lane >> 4;
    const float qscale = 0.08838834764831845f * 1.4426950408889634f; // 1/sqrt(128)*log2(e)

    const u16* kbase  = kb + ((size_t)(b * 4 + kvh) * SEQ) * 128;
    const u16* vtbase = vt + ((size_t)(b * 4 + kvh) * 128) * SEQ;

    // Q A-frags in registers, pre-scaled: A[m=c16][k=quad*8+e]
    bf16x8 qfA[4], qfB[4];
    {
        const u16* qpA = qb + (((size_t)(b * 16 + h)) * SEQ + qA * 64 + w * 16 + c16) * 128;
        const u16* qpB = qb + (((size_t)(b * 16 + h)) * SEQ + qB * 64 + w * 16 + c16) * 128;
#pragma unroll
        for (int kk = 0; kk < 4; ++kk) {
            bf16x8 ta = *(const bf16x8*)(qpA + kk * 32 + quad * 8);
            bf16x8 tb = *(const bf16x8*)(qpB + kk * 32 + quad * 8);
#pragma unroll
            for (int e = 0; e < 8; ++e) {
                ta[e] = (__bf16)((float)ta[e] * qscale);
                tb[e] = (__bf16)((float)tb[e] * qscale);
            }
            qfA[kk] = ta; qfB[kk] = tb;
        }
    }

    // staging source offsets (u16 units into a 16KB tile); 16 chunks of 1KB over 4 waves
    int ksrc[4], vsrc[4];
#pragma unroll
    for (int it = 0; it < 4; ++it) {
        int o  = (it * 4 + w) * 1024 + lane * 16;   // physical byte offset in 16KB tile
        int kk = o >> 12;                            // K panel (d-chunk) 0..3
        int r  = (o >> 6) & 63;                      // kcol
        int c  = (o >> 4) & 3;                       // 16B chunk in row
        ksrc[it] = r * 128 + kk * 32 + c * 8;
        int p2 = o >> 13;                            // V panel (kcol-chunk) 0..1
        int d  = (o >> 6) & 127;                     // d
        vsrc[it] = d * SEQ + p2 * 32 + c * 8;
    }

    const int nB = qB + 1;                  // 64-col k-tiles needed by qB (>= qA+1 always)
    const int rowLA = qA * 64 + w * 16 + quad * 4;
    const int rowLB = qB * 64 + w * 16 + quad * 4;

    f32x4 oA[8] = {}, oB[8] = {};
    float lA[4] = {}, lB[4] = {};

    u16* KsF  = &Ks[0][0][0][0];
    u16* VtsF = &Vts[0][0][0][0];

    // prologue: stage tile 0 -> buf 0 (8 gl_lds16 per wave), then barrier-drain
#pragma unroll
    for (int it = 0; it < 4; ++it) {
        gl_lds16(kbase  + ksrc[it], KsF  + (it * 4 + w) * 512);
        gl_lds16(vtbase + vsrc[it], VtsF + (it * 4 + w) * 512);
    }
    __syncthreads();

    for (int kt = 0; kt < nB; ++kt) {
        const int cur = kt & 1;

        // issue next tile's DMA into the other buffer BEFORE compute (overlap)
        if (kt + 1 < nB) {
            const u16* kg = kbase  + (size_t)(kt + 1) * (64 * 128);
            const u16* vg = vtbase + (kt + 1) * 64;
            u16* kd = KsF  + ((kt + 1) & 1) * (4 * 64 * 32);
            u16* vd = VtsF + ((kt + 1) & 1) * (2 * 128 * 32);
#pragma unroll
            for (int it = 0; it < 4; ++it) {
                gl_lds16(kg + ksrc[it], kd + (it * 4 + w) * 512);
                gl_lds16(vg + vsrc[it], vd + (it * 4 + w) * 512);
            }
        }

        const bool doA = kt <= qA;

        // QK^T on current buffer (K-frags shared between A and B q-tiles)
        f32x4 sA[4] = {}, sB[4] = {};
        if (doA) {
#pragma unroll
            for (int kk = 0; kk < 4; ++kk)
#pragma unroll
                for (int j = 0; j < 4; ++j) {
                    bf16x8 kf = *(const bf16x8*)&Ks[cur][kk][j * 16 + c16][quad * 8];
                    sA[j] = __builtin_amdgcn_mfma_f32_16x16x32_bf16(qfA[kk], kf, sA[j], 0, 0, 0);
                    sB[j] = __builtin_amdgcn_mfma_f32_16x16x32_bf16(qfB[kk], kf, sB[j], 0, 0, 0);
                }
        } else {
#pragma unroll
            for (int kk = 0; kk < 4; ++kk)
#pragma unroll
                for (int j = 0; j < 4; ++j) {
                    bf16x8 kf = *(const bf16x8*)&Ks[cur][kk][j * 16 + c16][quad * 8];
                    sB[j] = __builtin_amdgcn_mfma_f32_16x16x32_bf16(qfB[kk], kf, sB[j], 0, 0, 0);
                }
        }

        if (doA && kt == qA) {
#pragma unroll
            for (int j = 0; j < 4; ++j)
#pragma unroll
                for (int rr = 0; rr < 4; ++rr)
                    if (kt * 64 + j * 16 + c16 > rowLA + rr) sA[j][rr] = -1e30f;
        }
        if (kt == qB) {
#pragma unroll
            for (int j = 0; j < 4; ++j)
#pragma unroll
                for (int rr = 0; rr < 4; ++rr)
                    if (kt * 64 + j * 16 + c16 > rowLB + rr) sB[j][rr] = -1e30f;
        }

        // exp2 -> P half-buffer -> A-frags (V-frags shared A/B in PV)
        bf16x8 paA[2], paB[2];
        if (doA) {
#pragma unroll
            for (int jj = 0; jj < 4; ++jj)
#pragma unroll
                for (int rr = 0; rr < 4; ++rr) {
                    float p = __builtin_amdgcn_exp2f(sA[jj][rr]);
                    lA[rr] += p;
                    int row = quad * 4 + rr;
                    *(__bf16*)&Ph[w][row][(((jj * 2 + (c16 >> 3)) + row) & 7) * 8 + (c16 & 7)] = (__bf16)p;
                }
#pragma unroll
            for (int k2 = 0; k2 < 2; ++k2)
                paA[k2] = *(const bf16x8*)&Ph[w][c16][(((k2 * 4 + quad) + c16) & 7) * 8];
        }
#pragma unroll
        for (int jj = 0; jj < 4; ++jj)
#pragma unroll
            for (int rr = 0; rr < 4; ++rr) {
                float p = __builtin_amdgcn_exp2f(sB[jj][rr]);
                lB[rr] += p;
                int row = quad * 4 + rr;
                *(__bf16*)&Ph[w][row][(((jj * 2 + (c16 >> 3)) + row) & 7) * 8 + (c16 & 7)] = (__bf16)p;
            }
#pragma unroll
        for (int k2 = 0; k2 < 2; ++k2)
            paB[k2] = *(const bf16x8*)&Ph[w][c16][(((k2 * 4 + quad) + c16) & 7) * 8];

        // PV on current buffer
        if (doA) {
#pragma unroll
            for (int k2 = 0; k2 < 2; ++k2)
#pragma unroll
                for (int nt = 0; nt < 8; ++nt) {
                    bf16x8 vf = *(const bf16x8*)&Vts[cur][k2][nt * 16 + c16][quad * 8];
                    oA[nt] = __builtin_amdgcn_mfma_f32_16x16x32_bf16(paA[k2], vf, oA[nt], 0, 0, 0);
                    oB[nt] = __builtin_amdgcn_mfma_f32_16x16x32_bf16(paB[k2], vf, oB[nt], 0, 0, 0);
                }
        } else {
#pragma unroll
            for (int k2 = 0; k2 < 2; ++k2)
#pragma unroll
                for (int nt = 0; nt < 8; ++nt) {
                    bf16x8 vf = *(const bf16x8*)&Vts[cur][k2][nt * 16 + c16][quad * 8];
                    oB[nt] = __builtin_amdgcn_mfma_f32_16x16x32_bf16(paB[k2], vf, oB[nt], 0, 0, 0);
                }
        }

        // single barrier per tile: drains next-tile DMA (landed during compute)
        // and fences buffer reuse.
        __syncthreads();
    }

    // epilogue: row-sum of l across the 16-lane col groups, normalize, store
    float liA[4], liB[4];
#pragma unroll
    for (int rr = 0; rr < 4; ++rr) {
        float la = lA[rr], lb = lB[rr];
        la += __shfl_xor(la, 1); lb += __shfl_xor(lb, 1);
        la += __shfl_xor(la, 2); lb += __shfl_xor(lb, 2);
        la += __shfl_xor(la, 4); lb += __shfl_xor(lb, 4);
        la += __shfl_xor(la, 8); lb += __shfl_xor(lb, 8);
        liA[rr] = 1.0f / la;     liB[rr] = 1.0f / lb;
    }
    const size_t rowGA = (size_t)b * SEQ + rowLA;
    const size_t rowGB = (size_t)b * SEQ + rowLB;
#pragma unroll
    for (int nt = 0; nt < 8; ++nt)
#pragma unroll
        for (int rr = 0; rr < 4; ++rr) {
            ob[(rowGA + rr) * 2048 + h * 128 + nt * 16 + c16] = f2bf(oA[nt][rr] * liA[rr]);
            ob[(rowGB + rr) * 2048 + h * 128 + nt * 16 + c16] = f2bf(oB[nt][rr] * liB[rr]);
        }
}

// ---------------------------------------------------------------- launch
extern "C" void kernel_launch(void* const* d_in, const int* in_sizes, int n_in,
                              void* d_out, int out_size, void* d_ws, size_t ws_size,
                              hipStream_t stream) {
    const float* x    = (const float*)d_in[0];
    const float* wq   = (const float*)d_in[1];
    const float* bq   = (const float*)d_in[2];
    const float* wk   = (const float*)d_in[3];
    const float* bk   = (const float*)d_in[4];
    const float* wv   = (const float*)d_in[5];
    const float* bv   = (const float*)d_in[6];
    const float* wo   = (const float*)d_in[7];
    const float* bo   = (const float*)d_in[8];
    const float* cosb = (const float*)d_in[9];
    const float* sinb = (const float*)d_in[10];
    float* out = (float*)d_out;

    char* ws = (char*)d_ws;
    // workspace layout (bytes); total ~52 MB (validated r2-r4)
    const size_t OFF_WQKV = 0;              // 12,582,912  packed [wq|wk|wv] bf16; later wo bf16
    const size_t OFF_BIAS = 12582912;       //     16,384  packed qkv bias f32
    const size_t OFF_QB   = 12599296;       // 16,777,216  q bf16 (B,16,S,128)
    const size_t OFF_KB   = 29376512;       //  4,194,304  k bf16 (B,4,S,128)
    const size_t OFF_VT   = 33570816;       //  4,194,304  v^T bf16 (B,4,128,S)
    const size_t OFF_XB   = 37765120;       // 16,777,216  x bf16; later attn out bf16

    u16*   wqkvb = (u16*)(ws + OFF_WQKV);
    u16*   wob   = (u16*)(ws + OFF_WQKV);   // reuse after GEMM1
    float* biasb = (float*)(ws + OFF_BIAS);
    u16*   qb2   = (u16*)(ws + OFF_QB);
    u16*   kb2   = (u16*)(ws + OFF_KB);
    u16*   vt2   = (u16*)(ws + OFF_VT);
    u16*   xb    = (u16*)(ws + OFF_XB);
    u16*   attnb = (u16*)(ws + OFF_XB);     // reuse after GEMM1

    // 1. fused prep: x->bf16, wq/wk/wv->bf16 packed, bias pack
    prep<<<4096, 256, 0, stream>>>(x, wq, wk, wv, bq, bk, bv, xb, wqkvb, biasb);

    // 2. qkv = x @ [wq|wk|wv]^T + bias, split-written bf16: q,k natural; v transposed
    gemm_bt<1><<<dim3(32, 24), 256, 0, stream>>>(xb, wqkvb, biasb, nullptr,
                                                 qb2, kb2, vt2, 4096, 3072, 2048);

    // 3. wo -> bf16 (reuses wqkv region; stream-ordered after GEMM1)
    cvt_f32_bf16<<<4096, 256, 0, stream>>>(wo, wob, 1048576);

    // 4. RoPE in-place on q and k
    rope_inplace<<<((65536 + 16384) * 64) / 256, 256, 0, stream>>>(qb2, kb2, cosb, sinb);

    // 5. causal GQA MFMA attention v6 (dbuf 64-col tiles, 1 barrier/tile) -> (B*S, 2048) bf16
    attn_mfma<<<512, 256, 0, stream>>>(qb2, kb2, vt2, attnb);

    // 6. out = attn @ wo^T + bo  (fp32 to d_out)
    gemm_bt<0><<<dim3(32, 16), 256, 0, stream>>>(attnb, wob, bo, out,
                                                 nullptr, nullptr, nullptr, 4096, 2048, 2048);
}

// Round 6
// 347.235 us; speedup vs baseline: 1.0883x; 1.0001x over previous
//
#include <hip/hip_runtime.h>

typedef unsigned short u16;
typedef __bf16 bf16x8 __attribute__((ext_vector_type(8)));
typedef float  f32x4  __attribute__((ext_vector_type(4)));

#define SEQ 2048

__device__ __forceinline__ float bf2f(u16 u) {
    union { unsigned int i; float f; } c;
    c.i = ((unsigned int)u) << 16;
    return c.f;
}
__device__ __forceinline__ u16 f2bf(float f) {
    union { float f; unsigned int i; } c;
    c.f = f;
    unsigned int u = c.i;
    u += 0x7FFFu + ((u >> 16) & 1u);   // round-to-nearest-even
    return (u16)(u >> 16);
}

// async global->LDS, 16B per lane; lds dest = wave-uniform base + lane*16
__device__ __forceinline__ void gl_lds16(const u16* g, u16* l) {
    __builtin_amdgcn_global_load_lds(
        (const __attribute__((address_space(1))) unsigned int*)(g),
        (__attribute__((address_space(3))) unsigned int*)(l), 16, 0, 0);
}

__device__ __forceinline__ void cvt4(const float* s, u16* d) {
    float4 v = *(const float4*)s;
    ushort4 o;
    o.x = f2bf(v.x); o.y = f2bf(v.y); o.z = f2bf(v.z); o.w = f2bf(v.w);
    *(ushort4*)d = o;
}

// ---------------------------------------------------------------- fused prep
__global__ void prep(const float* __restrict__ x,
                     const float* __restrict__ wq, const float* __restrict__ wk,
                     const float* __restrict__ wv,
                     const float* __restrict__ bq, const float* __restrict__ bk,
                     const float* __restrict__ bv,
                     u16* __restrict__ xb, u16* __restrict__ wqkvb,
                     float* __restrict__ biasb)
{
    const int E0 = 2097152;            // x float4s
    const int E1 = E0 + 1048576;       // wq
    const int E2 = E1 + 262144;        // wk
    const int E3 = E2 + 262144;        // wv
    const int E4 = E3 + 768;           // bias float4s
    int i = blockIdx.x * blockDim.x + threadIdx.x;
    int stride = gridDim.x * blockDim.x;
    for (; i < E4; i += stride) {
        if (i < E0)      cvt4(x  + (size_t)i * 4,        xb    + (size_t)i * 4);
        else if (i < E1) cvt4(wq + (size_t)(i - E0) * 4, wqkvb + (size_t)(i - E0) * 4);
        else if (i < E2) cvt4(wk + (size_t)(i - E1) * 4, wqkvb + 4194304 + (size_t)(i - E1) * 4);
        else if (i < E3) cvt4(wv + (size_t)(i - E2) * 4, wqkvb + 5242880 + (size_t)(i - E2) * 4);
        else {
            int j = i - E3;            // 0..767
            const float* src = (j < 512) ? (bq + j * 4)
                             : (j < 640) ? (bk + (j - 512) * 4)
                                         : (bv + (j - 640) * 4);
            *(float4*)&biasb[j * 4] = *(const float4*)src;
        }
    }
}

__global__ void cvt_f32_bf16(const float* __restrict__ in, u16* __restrict__ out, int n4) {
    int i = blockIdx.x * blockDim.x + threadIdx.x;
    int stride = gridDim.x * blockDim.x;
    for (; i < n4; i += stride) cvt4(in + (size_t)i * 4, out + (size_t)i * 4);
}

// ---------------------------------------------------------------- GEMM C = A*B^T + bias
// global_load_lds staging (m97 pattern), plain layout.
// MODE 0: C fp32. MODE 1: qkv split q/k natural (B,H,S,128), v transposed (B,4,128,S).
template<int MODE>
__global__ __launch_bounds__(256) void gemm_bt(
    const u16* __restrict__ A, const u16* __restrict__ B,
    const float* __restrict__ bias, float* __restrict__ C,
    u16* __restrict__ qb, u16* __restrict__ kb, u16* __restrict__ vt,
    int M, int N, int K)
{
    __shared__ __align__(16) u16 lA[128 * 32];
    __shared__ __align__(16) u16 lB[128 * 32];
    const int tid   = threadIdx.x;
    const int lane  = tid & 63;
    const int wave  = tid >> 6;
    const int waveM = (wave >> 1) * 64;
    const int waveN = (wave & 1) * 64;
    const int bm = blockIdx.x * 128;
    const int bn = blockIdx.y * 128;
    const int lrow = lane & 15;
    const int koff = (lane >> 4) * 8;

    f32x4 acc[4][4] = {};

    for (int k0 = 0; k0 < K; k0 += 32) {
        __syncthreads();
#pragma unroll
        for (int p = 0; p < 2; ++p) {
            int idx = p * 256 + tid;    // 0..511
            int row = idx >> 2;         // 0..127
            int ch  = idx & 3;          // 16B chunk
            gl_lds16(&A[(size_t)(bm + row) * K + k0 + ch * 8], &lA[(p * 256 + wave * 64) * 8]);
            gl_lds16(&B[(size_t)(bn + row) * K + k0 + ch * 8], &lB[(p * 256 + wave * 64) * 8]);
        }
        __syncthreads();

        bf16x8 af[4], bfr[4];
#pragma unroll
        for (int i = 0; i < 4; ++i)
            af[i] = *(const bf16x8*)&lA[(waveM + i * 16 + lrow) * 32 + koff];
#pragma unroll
        for (int j = 0; j < 4; ++j)
            bfr[j] = *(const bf16x8*)&lB[(waveN + j * 16 + lrow) * 32 + koff];
#pragma unroll
        for (int i = 0; i < 4; ++i)
#pragma unroll
            for (int j = 0; j < 4; ++j)
                acc[i][j] = __builtin_amdgcn_mfma_f32_16x16x32_bf16(
                    af[i], bfr[j], acc[i][j], 0, 0, 0);
    }

    const int r4 = (lane >> 4) * 4;
    const int cn = lane & 15;
#pragma unroll
    for (int i = 0; i < 4; ++i) {
#pragma unroll
        for (int j = 0; j < 4; ++j) {
            int row0 = bm + waveM + i * 16 + r4;
            int col  = bn + waveN + j * 16 + cn;
            float bc = bias[col];
#pragma unroll
            for (int r = 0; r < 4; ++r) {
                float val = acc[i][j][r] + bc;
                if (MODE == 0) {
                    C[(size_t)(row0 + r) * N + col] = val;
                } else {
                    int row = row0 + r;
                    int b = row >> 11;          // row = b*2048 + s
                    int s = row & 2047;
                    int d = col & 127;
                    u16 o = f2bf(val);
                    if (col < 2048) {
                        int h = col >> 7;
                        qb[(((size_t)(b * 16 + h) * SEQ) + s) * 128 + d] = o;
                    } else if (col < 2560) {
                        int h = (col - 2048) >> 7;
                        kb[(((size_t)(b * 4 + h) * SEQ) + s) * 128 + d] = o;
                    } else {
                        int h = (col - 2560) >> 7;
                        vt[(((size_t)(b * 4 + h) * 128) + d) * SEQ + s] = o;  // V^T
                    }
                }
            }
        }
    }
}

// ---------------------------------------------------------------- RoPE in-place on q and k
__global__ void rope_inplace(u16* __restrict__ qb, u16* __restrict__ kb,
                             const float* __restrict__ cosb, const float* __restrict__ sinb)
{
    const int n = (65536 + 16384) * 64;
    int i = blockIdx.x * blockDim.x + threadIdx.x;
    if (i >= n) return;
    int d0  = i & 63;
    int row = i >> 6;
    u16* base;
    if (row < 65536) base = qb + (size_t)row * 128;
    else             base = kb + (size_t)(row - 65536) * 128;
    int s = row & (SEQ - 1);
    float c  = cosb[s * 128 + d0];
    float sn = sinb[s * 128 + d0];
    float a0 = bf2f(base[d0]);
    float a1 = bf2f(base[d0 + 64]);
    base[d0]      = f2bf(a0 * c - a1 * sn);
    base[d0 + 64] = f2bf(a1 * c + a0 * sn);
}

// ---------------------------------------------------------------- MFMA flash attention v7
// LDS-throughput analysis (r5): 36 ds_read_b128/wave/tile x 8 waves x 12cy ~ 3456cy/tile/CU
// vs 620cy MFMA -> kernel is LDS-read bound (explains MfmaUtil 16%, null pipelining gains).
// v7 cuts LDS read instructions ~33% via wave->tile specialization:
//   waves 0,1 own q-tile A (32 rows each, 2x16-row subs); waves 2,3 own q-tile B.
//   Each wave's 2 subs SHARE every K/V fragment read (same 36 reads now cover 32 rows
//   of one tile). On kt>qA tiles, A-waves skip ALL reads+MFMA (wave-uniform branch).
// Keeps: v6 dbuf 64-col tiles / 1 barrier per tile, v5 XCD slice swizzle, 72KB LDS.
__global__ __launch_bounds__(256, 2) void attn_mfma(
    const u16* __restrict__ qb, const u16* __restrict__ kb,
    const u16* __restrict__ vt, u16* __restrict__ ob)
{
    __shared__ __align__(16) u16 Ks[2][4][64][32];    // 2x16KB: [buf][d-chunk][kcol][32]
    __shared__ __align__(16) u16 Vts[2][2][128][32];  // 2x16KB: [buf][kcol-chunk][d][32]
    __shared__ __align__(16) u16 Ph[4][16][64];       // 8KB: per-wave rot-swizzled P

    // flat-grid decode: id&7 = (b,kvh) slice (XCD-pinned), id>>3 = (pair, h_lo)
    const int id   = blockIdx.x;
    const int s8   = id & 7;
    const int n    = id >> 3;          // 0..63
    const int pair = n & 15;
    const int h_lo = n >> 4;           // 0..3
    const int b    = s8 >> 2;
    const int kvh  = s8 & 3;
    const int h    = kvh * 4 + h_lo;
    const int qA   = pair, qB = 31 - pair;

    const int tid  = threadIdx.x;
    const int lane = tid & 63;
    const int w    = tid >> 6;
    const int c16  = lane & 15;
    const int quad = lane >> 4;
    const int T    = w >> 1;           // 0: tile A, 1: tile B
    const int sub  = w & 1;            // 32-row half within the tile
    const int qT   = T ? qB : qA;
    const float qscale = 0.08838834764831845f * 1.4426950408889634f; // 1/sqrt(128)*log2(e)

    const u16* kbase  = kb + ((size_t)(b * 4 + kvh) * SEQ) * 128;
    const u16* vtbase = vt + ((size_t)(b * 4 + kvh) * 128) * 128 * (SEQ / 128); // = *SEQ

    // Q A-frags in registers, pre-scaled: qf[s][kk], rows qT*64 + sub*32 + s*16 + c16
    bf16x8 qf[2][4];
#pragma unroll
    for (int s = 0; s < 2; ++s) {
        const u16* qp = qb + (((size_t)(b * 16 + h)) * SEQ + qT * 64 + sub * 32 + s * 16 + c16) * 128;
#pragma unroll
        for (int kk = 0; kk < 4; ++kk) {
            bf16x8 t = *(const bf16x8*)(qp + kk * 32 + quad * 8);
#pragma unroll
            for (int e = 0; e < 8; ++e) t[e] = (__bf16)((float)t[e] * qscale);
            qf[s][kk] = t;
        }
    }

    // staging source offsets (u16 units into a 16KB tile); 16 chunks of 1KB over 4 waves
    int ksrc[4], vsrc[4];
#pragma unroll
    for (int it = 0; it < 4; ++it) {
        int o  = (it * 4 + w) * 1024 + lane * 16;   // physical byte offset in 16KB tile
        int kk = o >> 12;                            // K panel (d-chunk) 0..3
        int r  = (o >> 6) & 63;                      // kcol
        int c  = (o >> 4) & 3;                       // 16B chunk in row
        ksrc[it] = r * 128 + kk * 32 + c * 8;
        int p2 = o >> 13;                            // V panel (kcol-chunk) 0..1
        int d  = (o >> 6) & 127;                     // d
        vsrc[it] = d * SEQ + p2 * 32 + c * 8;
    }

    const int nB = qB + 1;                  // 64-col k-tiles staged (covers both tiles)
    const int rowL0 = qT * 64 + sub * 32 + quad * 4;   // local row base (s=0)

    f32x4 o[2][8] = {};
    float l[2][4] = {};

    u16* KsF  = &Ks[0][0][0][0];
    u16* VtsF = &Vts[0][0][0][0];

    // prologue: stage tile 0 -> buf 0 (8 gl_lds16 per wave), then barrier-drain
#pragma unroll
    for (int it = 0; it < 4; ++it) {
        gl_lds16(kbase  + ksrc[it], KsF  + (it * 4 + w) * 512);
        gl_lds16(vtbase + vsrc[it], VtsF + (it * 4 + w) * 512);
    }
    __syncthreads();

    for (int kt = 0; kt < nB; ++kt) {
        const int cur = kt & 1;

        // issue next tile's DMA into the other buffer BEFORE compute (overlap)
        if (kt + 1 < nB) {
            const u16* kg = kbase  + (size_t)(kt + 1) * (64 * 128);
            const u16* vg = vtbase + (kt + 1) * 64;
            u16* kd = KsF  + ((kt + 1) & 1) * (4 * 64 * 32);
            u16* vd = VtsF + ((kt + 1) & 1) * (2 * 128 * 32);
#pragma unroll
            for (int it = 0; it < 4; ++it) {
                gl_lds16(kg + ksrc[it], kd + (it * 4 + w) * 512);
                gl_lds16(vg + vsrc[it], vd + (it * 4 + w) * 512);
            }
        }

        // wave-uniform activity: B-waves always, A-waves only while kt <= qA
        if (T == 1 || kt <= qA) {
            // QK^T: K-frags shared across this wave's two 16-row subs
            f32x4 sS[2][4] = {};
#pragma unroll
            for (int kk = 0; kk < 4; ++kk)
#pragma unroll
                for (int j = 0; j < 4; ++j) {
                    bf16x8 kf = *(const bf16x8*)&Ks[cur][kk][j * 16 + c16][quad * 8];
                    sS[0][j] = __builtin_amdgcn_mfma_f32_16x16x32_bf16(qf[0][kk], kf, sS[0][j], 0, 0, 0);
                    sS[1][j] = __builtin_amdgcn_mfma_f32_16x16x32_bf16(qf[1][kk], kf, sS[1][j], 0, 0, 0);
                }

            // causal mask on this tile's diagonal k-tile
            if (kt == qT) {
#pragma unroll
                for (int s = 0; s < 2; ++s)
#pragma unroll
                    for (int j = 0; j < 4; ++j)
#pragma unroll
                        for (int rr = 0; rr < 4; ++rr)
                            if (kt * 64 + j * 16 + c16 > rowL0 + s * 16 + rr) sS[s][j][rr] = -1e30f;
            }

            // softmax per sub: exp2 -> Ph (rot-swizzled) -> pa frags
            bf16x8 pa[2][2];
#pragma unroll
            for (int s = 0; s < 2; ++s) {
#pragma unroll
                for (int jj = 0; jj < 4; ++jj)
#pragma unroll
                    for (int rr = 0; rr < 4; ++rr) {
                        float p = __builtin_amdgcn_exp2f(sS[s][jj][rr]);
                        l[s][rr] += p;
                        int row = quad * 4 + rr;
                        *(__bf16*)&Ph[w][row][(((jj * 2 + (c16 >> 3)) + row) & 7) * 8 + (c16 & 7)] = (__bf16)p;
                    }
#pragma unroll
                for (int k2 = 0; k2 < 2; ++k2)
                    pa[s][k2] = *(const bf16x8*)&Ph[w][c16][(((k2 * 4 + quad) + c16) & 7) * 8];
            }

            // PV: V-frags shared across the two subs
#pragma unroll
            for (int k2 = 0; k2 < 2; ++k2)
#pragma unroll
                for (int nt = 0; nt < 8; ++nt) {
                    bf16x8 vf = *(const bf16x8*)&Vts[cur][k2][nt * 16 + c16][quad * 8];
                    o[0][nt] = __builtin_amdgcn_mfma_f32_16x16x32_bf16(pa[0][k2], vf, o[0][nt], 0, 0, 0);
                    o[1][nt] = __builtin_amdgcn_mfma_f32_16x16x32_bf16(pa[1][k2], vf, o[1][nt], 0, 0, 0);
                }
        }

        // single barrier per tile: drains next-tile DMA (landed during compute)
        // and fences buffer reuse.
        __syncthreads();
    }

    // epilogue: row-sum of l across the 16-lane col groups, normalize, store
#pragma unroll
    for (int s = 0; s < 2; ++s) {
        float li[4];
#pragma unroll
        for (int rr = 0; rr < 4; ++rr) {
            float la = l[s][rr];
            la += __shfl_xor(la, 1);
            la += __shfl_xor(la, 2);
            la += __shfl_xor(la, 4);
            la += __shfl_xor(la, 8);
            li[rr] = 1.0f / la;
        }
        const size_t rowG = (size_t)b * SEQ + rowL0 + s * 16;
#pragma unroll
        for (int nt = 0; nt < 8; ++nt)
#pragma unroll
            for (int rr = 0; rr < 4; ++rr)
                ob[(rowG + rr) * 2048 + h * 128 + nt * 16 + c16] = f2bf(o[s][nt][rr] * li[rr]);
    }
}

// ---------------------------------------------------------------- launch
extern "C" void kernel_launch(void* const* d_in, const int* in_sizes, int n_in,
                              void* d_out, int out_size, void* d_ws, size_t ws_size,
                              hipStream_t stream) {
    const float* x    = (const float*)d_in[0];
    const float* wq   = (const float*)d_in[1];
    const float* bq   = (const float*)d_in[2];
    const float* wk   = (const float*)d_in[3];
    const float* bk   = (const float*)d_in[4];
    const float* wv   = (const float*)d_in[5];
    const float* bv   = (const float*)d_in[6];
    const float* wo   = (const float*)d_in[7];
    const float* bo   = (const float*)d_in[8];
    const float* cosb = (const float*)d_in[9];
    const float* sinb = (const float*)d_in[10];
    float* out = (float*)d_out;

    char* ws = (char*)d_ws;
    // workspace layout (bytes); total ~52 MB (validated r2-r4)
    const size_t OFF_WQKV = 0;              // 12,582,912  packed [wq|wk|wv] bf16; later wo bf16
    const size_t OFF_BIAS = 12582912;       //     16,384  packed qkv bias f32
    const size_t OFF_QB   = 12599296;       // 16,777,216  q bf16 (B,16,S,128)
    const size_t OFF_KB   = 29376512;       //  4,194,304  k bf16 (B,4,S,128)
    const size_t OFF_VT   = 33570816;       //  4,194,304  v^T bf16 (B,4,128,S)
    const size_t OFF_XB   = 37765120;       // 16,777,216  x bf16; later attn out bf16

    u16*   wqkvb = (u16*)(ws + OFF_WQKV);
    u16*   wob   = (u16*)(ws + OFF_WQKV);   // reuse after GEMM1
    float* biasb = (float*)(ws + OFF_BIAS);
    u16*   qb2   = (u16*)(ws + OFF_QB);
    u16*   kb2   = (u16*)(ws + OFF_KB);
    u16*   vt2   = (u16*)(ws + OFF_VT);
    u16*   xb    = (u16*)(ws + OFF_XB);
    u16*   attnb = (u16*)(ws + OFF_XB);     // reuse after GEMM1

    // 1. fused prep: x->bf16, wq/wk/wv->bf16 packed, bias pack
    prep<<<4096, 256, 0, stream>>>(x, wq, wk, wv, bq, bk, bv, xb, wqkvb, biasb);

    // 2. qkv = x @ [wq|wk|wv]^T + bias, split-written bf16: q,k natural; v transposed
    gemm_bt<1><<<dim3(32, 24), 256, 0, stream>>>(xb, wqkvb, biasb, nullptr,
                                                 qb2, kb2, vt2, 4096, 3072, 2048);

    // 3. wo -> bf16 (reuses wqkv region; stream-ordered after GEMM1)
    cvt_f32_bf16<<<4096, 256, 0, stream>>>(wo, wob, 1048576);

    // 4. RoPE in-place on q and k
    rope_inplace<<<((65536 + 16384) * 64) / 256, 256, 0, stream>>>(qb2, kb2, cosb, sinb);

    // 5. causal GQA MFMA attention v7 (wave->tile specialization) -> (B*S, 2048) bf16
    attn_mfma<<<512, 256, 0, stream>>>(qb2, kb2, vt2, attnb);

    // 6. out = attn @ wo^T + bo  (fp32 to d_out)
    gemm_bt<0><<<dim3(32, 16), 256, 0, stream>>>(attnb, wob, bo, out,
                                                 nullptr, nullptr, nullptr, 4096, 2048, 2048);
}